// Round 9
// baseline (173.837 us; speedup 1.0000x reference)
//
#include <hip/hip_runtime.h>
#include <math.h>

// InfoNCE, exact JAX threefry2x32 negative-sampling reproduction.
// I=4096, E=16384, D=64.
//
// R9 (from R5/R8 @161us prof, VALUBusy ~65%):
//  - positives via per-thread 64-bit register bitmask (adj is {0,1}; bit
//    4i+c), extracted ONCE after the stream loop -> deletes 8 of 16
//    wave-append calls (ballots+branches+append bodies) per iteration.
//  - item-row norms hoisted to a one-time preamble (removes 2 barrier
//    pairs + dependent-load stalls from phase 2).
//  - __builtin_rotateleft32 pins v_alignbit single-op rotates.
//  - everything else identical to R5 (best measured structure).
// R6/R7 lesson kept: VGPR<=64; no launch_bounds min-wave pinning.

constexpr int D      = 64;
constexpr int PCAP   = 96;    // num_pos ~ Binom(16384,.002): mean 33
constexpr int CCAP   = 192;   // bin-0 negs ~ Binom(16384,1/256): mean 64
constexpr int SELCAP = 128;   // k <= npos <= PCAP

typedef int int4v __attribute__((ext_vector_type(4)));
typedef unsigned long long u64;

// JAX threefry2x32, key = (0, 42) from jax.random.key(42).
__device__ __forceinline__ void threefry2x32(unsigned x0, unsigned x1,
                                             unsigned& o0, unsigned& o1) {
  const unsigned ks0 = 0u;
  const unsigned ks1 = 42u;
  const unsigned ks2 = 0x1BD11BDAu ^ 0u ^ 42u;
  x0 += ks0; x1 += ks1;
#define TF_R(r) { x0 += x1; x1 = __builtin_rotateleft32(x1, (r)) ^ x0; }
  TF_R(13) TF_R(15) TF_R(26) TF_R(6)
  x0 += ks1; x1 += ks2 + 1u;
  TF_R(17) TF_R(29) TF_R(16) TF_R(24)
  x0 += ks2; x1 += ks0 + 2u;
  TF_R(13) TF_R(15) TF_R(26) TF_R(6)
  x0 += ks0; x1 += ks1 + 3u;
  TF_R(17) TF_R(29) TF_R(16) TF_R(24)
  x0 += ks1; x1 += ks2 + 4u;
  TF_R(13) TF_R(15) TF_R(26) TF_R(6)
  x0 += ks2; x1 += ks0 + 5u;
#undef TF_R
  o0 = x0; o1 = x1;
}

// count of set mask bits strictly below my lane
__device__ __forceinline__ int lane_prior(unsigned long long m) {
  return (int)__builtin_amdgcn_mbcnt_hi(
      (unsigned)(m >> 32), __builtin_amdgcn_mbcnt_lo((unsigned)m, 0u));
}

// wave-cooperative list append: one leader atomic, readlane broadcast.
// Uniform-skips entirely when no lane matches (the common case).
__device__ __forceinline__ void wave_append(bool pred, int e,
                                            int* cnt, int* list, int cap) {
  unsigned long long m = __ballot(pred);
  if (m) {
    const int lane = threadIdx.x & 63;
    const int leader = __builtin_ctzll(m);
    int base = 0;
    if (lane == leader) base = atomicAdd(cnt, (int)__popcll(m));
    base = __builtin_amdgcn_readlane(base, leader);
    if (pred) {
      int s = base + lane_prior(m);
      if (s < cap) list[s] = e;
    }
  }
}

__device__ __forceinline__ void wave_append2(bool pred, int e, unsigned key,
                                             int* cnt, int* li, unsigned* lk,
                                             int cap) {
  unsigned long long m = __ballot(pred);
  if (m) {
    const int lane = threadIdx.x & 63;
    const int leader = __builtin_ctzll(m);
    int base = 0;
    if (lane == leader) base = atomicAdd(cnt, (int)__popcll(m));
    base = __builtin_amdgcn_readlane(base, leader);
    if (pred) {
      int s = base + lane_prior(m);
      if (s < cap) { li[s] = e; lk[s] = key; }
    }
  }
}

__device__ __forceinline__ float dot_sim(const float* __restrict__ ent, int e,
                                         const float* itemn) {
  const float4* er = (const float4*)(ent + ((size_t)e << 6));
  float dot = 0.f, ss = 0.f;
#pragma unroll
  for (int q = 0; q < 16; ++q) {
    float4 f = er[q];
    dot += itemn[4 * q + 0] * f.x + itemn[4 * q + 1] * f.y +
           itemn[4 * q + 2] * f.z + itemn[4 * q + 3] * f.w;
    ss += f.x * f.x + f.y * f.y + f.z * f.z + f.w * f.w;
  }
  return dot * (1.0f / sqrtf(ss));
}

__device__ __forceinline__ float block_max(float v, float* wred, int t) {
#pragma unroll
  for (int off = 32; off; off >>= 1) v = fmaxf(v, __shfl_xor(v, off, 64));
  __syncthreads();
  if ((t & 63) == 0) wred[t >> 6] = v;
  __syncthreads();
  return fmaxf(fmaxf(wred[0], wred[1]), fmaxf(wred[2], wred[3]));
}

__device__ __forceinline__ float block_sum(float v, float* wred, int t) {
#pragma unroll
  for (int off = 32; off; off >>= 1) v += __shfl_xor(v, off, 64);
  __syncthreads();
  if ((t & 63) == 0) wred[t >> 6] = v;
  __syncthreads();
  return wred[0] + wred[1] + wred[2] + wred[3];
}

// One block per row pair (iA, iA+I/2): element j of row iA is out0 of
// threefry(j_glob, j_glob+2^25); row iB's element j is out1 of the SAME eval.
template <bool WSOUT>
__global__ __launch_bounds__(256) void infonce_mono(
    const float* __restrict__ item, const float* __restrict__ ent,
    const int* __restrict__ adj, int I, int E,
    float* __restrict__ loss, int* __restrict__ cnt,
    double* __restrict__ accum, int* __restrict__ paircnt) {
  const int t = threadIdx.x;
  const int halfI = I >> 1;
  const int iA = blockIdx.x;
  const int iB = iA + halfI;
  const unsigned HALF = (unsigned)halfI * (unsigned)E;  // 2^25
  const unsigned baseA = (unsigned)iA * (unsigned)E;

  __shared__ int s_pos[2][PCAP];
  __shared__ int s_ci[2][CCAP];
  __shared__ unsigned s_ck[2][CCAP];
  __shared__ int s_sel[SELCAP];
  __shared__ int s_hist[256];
  __shared__ float s_itemn[2][D];
  __shared__ float s_wred[4];
  __shared__ int s_np[2], s_nc[2];
  __shared__ int s_nsel, s_bbin, s_cbef, s_fnc;

  if (t < 2) { s_np[t] = 0; s_nc[t] = 0; }
  // hoisted: both item rows normalized once (wave0 -> A, wave1 -> B)
  if (t < 128) {
    const int r = t >> 6, ln = t & 63;
    float iv = item[(size_t)(r ? iB : iA) * D + ln];
    float ss = iv * iv;
#pragma unroll
    for (int off = 32; off; off >>= 1) ss += __shfl_xor(ss, off, 64);
    s_itemn[r][ln] = iv * (1.0f / sqrtf(ss)) * (1.0f / 0.07f);
  }
  __syncthreads();

  // ---- Phase 1: adj stream + threefry + cand appends; pos -> reg bitmask ----
  const int niter = E >> 10;  // 1024 elements per block-iteration (<=16)
  u64 wposA = 0, wposB = 0;   // bit (4i+c): element 4t + 1024 i + c is positive
  const int4v* adjA = (const int4v*)(adj + (size_t)iA * E);
  const int4v* adjB = (const int4v*)(adj + (size_t)iB * E);
  for (int i = 0; i < niter; ++i) {
    const int v = t + (i << 8);
    int4v a4 = __builtin_nontemporal_load(&adjA[v]);
    int4v b4 = __builtin_nontemporal_load(&adjB[v]);
    const unsigned e0 = (unsigned)v * 4u;
    unsigned o0[4], o1[4];
#pragma unroll
    for (int c = 0; c < 4; ++c) {  // straight-line: 4 independent evals
      const unsigned x = baseA + e0 + c;
      threefry2x32(x, x + HALF, o0[c], o1[c]);
    }
    // adj values are {0,1} (bool.astype(int32)): nibble-pack directly
    const unsigned nibA = (a4[0] & 1) | ((a4[1] & 1) << 1) |
                          ((a4[2] & 1) << 2) | ((a4[3] & 1) << 3);
    const unsigned nibB = (b4[0] & 1) | ((b4[1] & 1) << 1) |
                          ((b4[2] & 1) << 2) | ((b4[3] & 1) << 3);
    wposA |= (u64)nibA << (4 * i);
    wposB |= (u64)nibB << (4 * i);
#pragma unroll
    for (int c = 0; c < 4; ++c) {
      const int e = (int)(e0 + c);
      wave_append2(!((nibA >> c) & 1) && (o0[c] >> 24) == 0u, e, o0[c] >> 9,
                   &s_nc[0], s_ci[0], s_ck[0], CCAP);
      wave_append2(!((nibB >> c) & 1) && (o1[c] >> 24) == 0u, e, o1[c] >> 9,
                   &s_nc[1], s_ci[1], s_ck[1], CCAP);
    }
  }
  // one-time positive extraction from register bitmasks (~30 threads active)
  {
    const int nA = (int)__popcll(wposA);
    if (nA) {
      int base = atomicAdd(&s_np[0], nA);
      u64 w = wposA;
      for (int j = 0; w; ++j) {
        const int b = (int)__builtin_ctzll(w);
        w &= w - 1;
        const int e = ((b >> 2) << 10) + (t << 2) + (b & 3);
        if (base + j < PCAP) s_pos[0][base + j] = e;
      }
    }
    const int nB = (int)__popcll(wposB);
    if (nB) {
      int base = atomicAdd(&s_np[1], nB);
      u64 w = wposB;
      for (int j = 0; w; ++j) {
        const int b = (int)__builtin_ctzll(w);
        w &= w - 1;
        const int e = ((b >> 2) << 10) + (t << 2) + (b & 3);
        if (base + j < PCAP) s_pos[1][base + j] = e;
      }
    }
  }
  __syncthreads();

  // ---- Phase 2: per-row selection + loss ----
  for (int r2 = 0; r2 < 2; ++r2) {
    const int row = r2 ? iB : iA;
    const int npT = s_np[r2];           // true count
    const int npos = min(npT, PCAP);
    const int k = min(npT, E - npT);    // NEG_RATIO = 1.0
    const bool valid = (npT > 0 && k > 0);  // block-uniform
    float rowloss = 0.f;
    bool fb = false;
    if (valid) {
      if (t == 0) s_nsel = 0;
      __syncthreads();
      int ncand = min(s_nc[r2], CCAP);
      int rneed = k;
      fb = (s_nc[r2] > CCAP) || (ncand < k) || (npT > PCAP);
      if (fb) {
        // ---- rare exact fallback: full row rescan, 256-bin histogram ----
        s_hist[t] = 0;
        if (t == 0) s_fnc = 0;
        __syncthreads();
        const int* adjR = adj + (size_t)row * E;
        for (int e = t; e < E; e += 256) {
          if (adjR[e] > 0) continue;
          unsigned o0, o1;
          threefry2x32(baseA + (unsigned)e, baseA + (unsigned)e + HALF, o0, o1);
          atomicAdd(&s_hist[(r2 ? o1 : o0) >> 24], 1);
        }
        __syncthreads();
        if (t == 0) {
          int cum = 0, b = 0;
          while (b < 255 && cum + s_hist[b] < k) { cum += s_hist[b]; ++b; }
          s_bbin = b; s_cbef = cum;
        }
        __syncthreads();
        const int b = s_bbin;
        for (int e = t; e < E; e += 256) {
          bool neg = (adjR[e] <= 0);
          unsigned o0, o1, bits = 0xFFFFFFFFu;
          if (neg) {
            threefry2x32(baseA + (unsigned)e, baseA + (unsigned)e + HALF, o0, o1);
            bits = r2 ? o1 : o0;
          }
          int b8 = (int)(bits >> 24);
          wave_append(neg && b8 < b, e, &s_nsel, s_sel, SELCAP);
          wave_append2(neg && b8 == b, e, bits >> 9,
                       &s_fnc, s_ci[r2], s_ck[r2], CCAP);
        }
        __syncthreads();
        ncand = min(s_fnc, CCAP);
        rneed = k - s_cbef;
      }

      // exact rank among candidates, stable tie-break (key, idx)
      for (int i = t; i < ncand; i += 256) {
        const unsigned mk = s_ck[r2][i];
        const int mi = s_ci[r2][i];
        int rank = 0;
        for (int c = 0; c < ncand; ++c) {
          const unsigned ck = s_ck[r2][c];
          const int ci = s_ci[r2][c];
          rank += (ck < mk || (ck == mk && ci < mi)) ? 1 : 0;
        }
        if (rank < rneed) {
          int s = atomicAdd(&s_nsel, 1);
          if (s < SELCAP) s_sel[s] = mi;
        }
      }
      __syncthreads();  // closes the rank-append section
      const int nsel = min(s_nsel, SELCAP);  // == k

      float myv = (t < nsel) ? dot_sim(ent, s_sel[t], s_itemn[r2]) : -INFINITY;
      const float m = block_max(myv, s_wred, t);
      float v2 = (t < nsel) ? expf(myv - m) : 0.f;
      const float S = block_sum(v2, s_wred, t);

      float lp = 0.f;
      if (!fb) {
        if (t < npos) {
          float sp = dot_sim(ent, s_pos[r2][t], s_itemn[r2]);
          float pm = fmaxf(sp, m);
          lp = logf(expf(sp - pm) + S * expf(m - pm)) + pm - sp;
        }
      } else {
        // pos list may be truncated in fallback: rescan adj for positives
        const int* adjR = adj + (size_t)row * E;
        for (int e = t; e < E; e += 256) {
          if (adjR[e] > 0) {
            float sp = dot_sim(ent, e, s_itemn[r2]);
            float pm = fmaxf(sp, m);
            lp += logf(expf(sp - pm) + S * expf(m - pm)) + pm - sp;
          }
        }
      }
      rowloss = block_sum(lp, s_wred, t);
    }
    if (WSOUT) {
      if (t == 0) { loss[row] = valid ? rowloss : 0.f; cnt[row] = valid ? npT : 0; }
    } else {
      if (valid && t == 0) {
        atomicAdd(accum, (double)rowloss);
        atomicAdd(paircnt, npT);
      }
    }
    __syncthreads();
  }
}

// Deterministic single-block tree reduction: out = sum(loss)/sum(cnt).
__global__ __launch_bounds__(256) void reduce_out(
    const float* __restrict__ loss, const int* __restrict__ cnt, int I,
    float* __restrict__ out) {
  const int t = threadIdx.x;
  __shared__ double s_l[256];
  __shared__ int s_n[256];
  double l = 0.0;
  int n = 0;
  for (int i = t; i < I; i += 256) { l += (double)loss[i]; n += cnt[i]; }
  s_l[t] = l; s_n[t] = n;
  __syncthreads();
  for (int off = 128; off; off >>= 1) {
    if (t < off) { s_l[t] += s_l[t + off]; s_n[t] += s_n[t + off]; }
    __syncthreads();
  }
  if (t == 0) out[0] = (s_n[0] > 0) ? (float)(s_l[0] / (double)s_n[0]) : 0.f;
}

__global__ void infonce_init(double* accum, int* cnt) {
  if (threadIdx.x == 0 && blockIdx.x == 0) { accum[0] = 0.0; cnt[0] = 0; }
}

__global__ void infonce_final(const double* __restrict__ accum,
                              const int* __restrict__ cnt,
                              float* __restrict__ out) {
  if (threadIdx.x == 0 && blockIdx.x == 0) {
    int n = cnt[0];
    out[0] = (n > 0) ? (float)(accum[0] / (double)n) : 0.f;
  }
}

extern "C" void kernel_launch(void* const* d_in, const int* in_sizes, int n_in,
                              void* d_out, int out_size, void* d_ws, size_t ws_size,
                              hipStream_t stream) {
  const float* item = (const float*)d_in[0];
  const float* ent  = (const float*)d_in[1];
  const int*   adj  = (const int*)d_in[2];
  const int I = in_sizes[0] / D;   // 4096
  const int E = in_sizes[1] / D;   // 16384

  const size_t need = (size_t)I * 8;  // loss[I] f32 + cnt[I] i32
  // bitmask path needs E/1024 <= 16 iterations (64-bit word)
  if (ws_size >= need && (I % 2) == 0 && (E % 1024) == 0 && E <= 16384) {
    float* lossb = (float*)d_ws;
    int*   cntb  = (int*)(lossb + I);
    infonce_mono<true><<<I / 2, 256, 0, stream>>>(item, ent, adj, I, E,
                                                  lossb, cntb, nullptr, nullptr);
    reduce_out<<<1, 256, 0, stream>>>(lossb, cntb, I, (float*)d_out);
  } else {
    double* accum   = (double*)d_ws;
    int*    paircnt = (int*)((char*)d_ws + 8);
    infonce_init<<<1, 64, 0, stream>>>(accum, paircnt);
    infonce_mono<false><<<I / 2, 256, 0, stream>>>(item, ent, adj, I, E,
                                                   nullptr, nullptr, accum, paircnt);
    infonce_final<<<1, 64, 0, stream>>>(accum, paircnt, (float*)d_out);
  }
}

// Round 10
// 153.046 us; speedup vs baseline: 1.1358x; 1.1358x over previous
//
#include <hip/hip_runtime.h>
#include <math.h>

// InfoNCE, exact JAX threefry2x32 negative-sampling reproduction.
// I=4096, E=16384, D=64.
//
// R10 = R8 (best: 161us prof) with ONE change: grouped-ballot appends.
// Instead of 16 ballot+branch sites per iteration (4 elems x 4 lists),
// build a 4-bit candidate/positive mask per row and ballot ONCE per
// list per iteration; the rare taken path (~0.3-0.6/iter) does direct
// per-lane LDS atomic appends (selection is order-independent).
// R9's bitmask-positives + hoisted norms REGRESSED (181us) - reverted.
// R6/R7 lesson kept: VGPR<=64, no launch_bounds min-wave pinning.

constexpr int D      = 64;
constexpr int PCAP   = 96;    // num_pos ~ Binom(16384,.002): mean 33
constexpr int CCAP   = 192;   // bin-0 negs ~ Binom(16384,1/256): mean 64
constexpr int SELCAP = 128;   // k <= npos <= PCAP

typedef int int4v __attribute__((ext_vector_type(4)));

// JAX threefry2x32, key = (0, 42) from jax.random.key(42).
__device__ __forceinline__ void threefry2x32(unsigned x0, unsigned x1,
                                             unsigned& o0, unsigned& o1) {
  const unsigned ks0 = 0u;
  const unsigned ks1 = 42u;
  const unsigned ks2 = 0x1BD11BDAu ^ 0u ^ 42u;
  x0 += ks0; x1 += ks1;
#define TF_R(r) { x0 += x1; x1 = (x1 << (r)) | (x1 >> (32 - (r))); x1 ^= x0; }
  TF_R(13) TF_R(15) TF_R(26) TF_R(6)
  x0 += ks1; x1 += ks2 + 1u;
  TF_R(17) TF_R(29) TF_R(16) TF_R(24)
  x0 += ks2; x1 += ks0 + 2u;
  TF_R(13) TF_R(15) TF_R(26) TF_R(6)
  x0 += ks0; x1 += ks1 + 3u;
  TF_R(17) TF_R(29) TF_R(16) TF_R(24)
  x0 += ks1; x1 += ks2 + 4u;
  TF_R(13) TF_R(15) TF_R(26) TF_R(6)
  x0 += ks2; x1 += ks0 + 5u;
#undef TF_R
  o0 = x0; o1 = x1;
}

// count of set mask bits strictly below my lane
__device__ __forceinline__ int lane_prior(unsigned long long m) {
  return (int)__builtin_amdgcn_mbcnt_hi(
      (unsigned)(m >> 32), __builtin_amdgcn_mbcnt_lo((unsigned)m, 0u));
}

// wave-cooperative list append (fallback path only)
__device__ __forceinline__ void wave_append(bool pred, int e,
                                            int* cnt, int* list, int cap) {
  unsigned long long m = __ballot(pred);
  if (m) {
    const int lane = threadIdx.x & 63;
    const int leader = __builtin_ctzll(m);
    int base = 0;
    if (lane == leader) base = atomicAdd(cnt, (int)__popcll(m));
    base = __builtin_amdgcn_readlane(base, leader);
    if (pred) {
      int s = base + lane_prior(m);
      if (s < cap) list[s] = e;
    }
  }
}

__device__ __forceinline__ void wave_append2(bool pred, int e, unsigned key,
                                             int* cnt, int* li, unsigned* lk,
                                             int cap) {
  unsigned long long m = __ballot(pred);
  if (m) {
    const int lane = threadIdx.x & 63;
    const int leader = __builtin_ctzll(m);
    int base = 0;
    if (lane == leader) base = atomicAdd(cnt, (int)__popcll(m));
    base = __builtin_amdgcn_readlane(base, leader);
    if (pred) {
      int s = base + lane_prior(m);
      if (s < cap) { li[s] = e; lk[s] = key; }
    }
  }
}

__device__ __forceinline__ float dot_sim(const float* __restrict__ ent, int e,
                                         const float* itemn) {
  const float4* er = (const float4*)(ent + ((size_t)e << 6));
  float dot = 0.f, ss = 0.f;
#pragma unroll
  for (int q = 0; q < 16; ++q) {
    float4 f = er[q];
    dot += itemn[4 * q + 0] * f.x + itemn[4 * q + 1] * f.y +
           itemn[4 * q + 2] * f.z + itemn[4 * q + 3] * f.w;
    ss += f.x * f.x + f.y * f.y + f.z * f.z + f.w * f.w;
  }
  return dot * (1.0f / sqrtf(ss));
}

__device__ __forceinline__ float block_max(float v, float* wred, int t) {
#pragma unroll
  for (int off = 32; off; off >>= 1) v = fmaxf(v, __shfl_xor(v, off, 64));
  __syncthreads();
  if ((t & 63) == 0) wred[t >> 6] = v;
  __syncthreads();
  return fmaxf(fmaxf(wred[0], wred[1]), fmaxf(wred[2], wred[3]));
}

__device__ __forceinline__ float block_sum(float v, float* wred, int t) {
#pragma unroll
  for (int off = 32; off; off >>= 1) v += __shfl_xor(v, off, 64);
  __syncthreads();
  if ((t & 63) == 0) wred[t >> 6] = v;
  __syncthreads();
  return wred[0] + wred[1] + wred[2] + wred[3];
}

// One block per row pair (iA, iA+I/2): element j of row iA is out0 of
// threefry(j_glob, j_glob+2^25); row iB's element j is out1 of the SAME eval.
template <bool WSOUT>
__global__ __launch_bounds__(256) void infonce_mono(
    const float* __restrict__ item, const float* __restrict__ ent,
    const int* __restrict__ adj, int I, int E,
    float* __restrict__ loss, int* __restrict__ cnt,
    double* __restrict__ accum, int* __restrict__ paircnt) {
  const int t = threadIdx.x;
  const int halfI = I >> 1;
  const int iA = blockIdx.x;
  const int iB = iA + halfI;
  const unsigned HALF = (unsigned)halfI * (unsigned)E;  // 2^25
  const unsigned baseA = (unsigned)iA * (unsigned)E;

  __shared__ int s_pos[2][PCAP];
  __shared__ int s_ci[2][CCAP];
  __shared__ unsigned s_ck[2][CCAP];
  __shared__ int s_sel[SELCAP];
  __shared__ int s_hist[256];
  __shared__ float s_itemn[D];
  __shared__ float s_wred[4];
  __shared__ int s_np[2], s_nc[2];
  __shared__ int s_nsel, s_bbin, s_cbef, s_fnc;
  __shared__ float s_scale;

  if (t < 2) { s_np[t] = 0; s_nc[t] = 0; }
  __syncthreads();

  // ---- Phase 1: adj stream + threefry + grouped-ballot appends ----
  const int nvec = E >> 2;
  const int4v* adjA = (const int4v*)(adj + (size_t)iA * E);
  const int4v* adjB = (const int4v*)(adj + (size_t)iB * E);
  for (int v = t; v < nvec; v += 256) {
    int4v a4 = __builtin_nontemporal_load(&adjA[v]);
    int4v b4 = __builtin_nontemporal_load(&adjB[v]);
    const unsigned e0 = (unsigned)v * 4u;
    unsigned o0[4], o1[4];
#pragma unroll
    for (int c = 0; c < 4; ++c) {  // straight-line: 4 independent evals
      const unsigned x = baseA + e0 + c;
      threefry2x32(x, x + HALF, o0[c], o1[c]);
    }
    // per-row 4-bit masks: positives and bin-0 candidates
    unsigned pmA = 0, pmB = 0, cmA = 0, cmB = 0;
#pragma unroll
    for (int c = 0; c < 4; ++c) {
      const bool pa = (a4[c] > 0), pb = (b4[c] > 0);
      pmA |= pa ? (1u << c) : 0u;
      pmB |= pb ? (1u << c) : 0u;
      cmA |= (!pa && (o0[c] >> 24) == 0u) ? (1u << c) : 0u;
      cmB |= (!pb && (o1[c] >> 24) == 0u) ? (1u << c) : 0u;
    }
    // one ballot per list per iteration; rare taken path does direct
    // per-lane atomics (selection set is order-independent).
    if (__ballot(pmA != 0)) {
#pragma unroll
      for (int c = 0; c < 4; ++c)
        if (pmA & (1u << c)) {
          int s = atomicAdd(&s_np[0], 1);
          if (s < PCAP) s_pos[0][s] = (int)(e0 + c);
        }
    }
    if (__ballot(pmB != 0)) {
#pragma unroll
      for (int c = 0; c < 4; ++c)
        if (pmB & (1u << c)) {
          int s = atomicAdd(&s_np[1], 1);
          if (s < PCAP) s_pos[1][s] = (int)(e0 + c);
        }
    }
    if (__ballot(cmA != 0)) {
#pragma unroll
      for (int c = 0; c < 4; ++c)
        if (cmA & (1u << c)) {
          int s = atomicAdd(&s_nc[0], 1);
          if (s < CCAP) { s_ci[0][s] = (int)(e0 + c); s_ck[0][s] = o0[c] >> 9; }
        }
    }
    if (__ballot(cmB != 0)) {
#pragma unroll
      for (int c = 0; c < 4; ++c)
        if (cmB & (1u << c)) {
          int s = atomicAdd(&s_nc[1], 1);
          if (s < CCAP) { s_ci[1][s] = (int)(e0 + c); s_ck[1][s] = o1[c] >> 9; }
        }
    }
  }
  __syncthreads();

  // ---- Phase 2: per-row selection + loss (identical to R5/R8) ----
  for (int r2 = 0; r2 < 2; ++r2) {
    const int row = r2 ? iB : iA;
    const int npos = min(s_np[r2], PCAP);
    const int k = min(npos, E - npos);  // NEG_RATIO = 1.0
    const bool valid = (npos > 0 && k > 0);  // block-uniform
    float rowloss = 0.f;
    if (valid) {
      if (t == 0) s_nsel = 0;
      __syncthreads();
      int ncand = min(s_nc[r2], CCAP);  // all candidates are negatives
      int rneed = k;
      if (s_nc[r2] > CCAP || ncand < k) {
        // ---- rare exact fallback: full row rescan, 256-bin histogram ----
        s_hist[t] = 0;
        if (t == 0) s_fnc = 0;
        __syncthreads();
        const int* adjR = adj + (size_t)row * E;
        for (int e = t; e < E; e += 256) {
          if (adjR[e] > 0) continue;
          unsigned o0, o1;
          threefry2x32(baseA + (unsigned)e, baseA + (unsigned)e + HALF, o0, o1);
          atomicAdd(&s_hist[(r2 ? o1 : o0) >> 24], 1);
        }
        __syncthreads();
        if (t == 0) {
          int cum = 0, b = 0;
          while (b < 255 && cum + s_hist[b] < k) { cum += s_hist[b]; ++b; }
          s_bbin = b; s_cbef = cum;
        }
        __syncthreads();
        const int b = s_bbin;
        for (int e = t; e < E; e += 256) {
          bool neg = (adjR[e] <= 0);
          unsigned o0, o1, bits = 0xFFFFFFFFu;
          if (neg) {
            threefry2x32(baseA + (unsigned)e, baseA + (unsigned)e + HALF, o0, o1);
            bits = r2 ? o1 : o0;
          }
          int b8 = (int)(bits >> 24);
          wave_append(neg && b8 < b, e, &s_nsel, s_sel, SELCAP);
          wave_append2(neg && b8 == b, e, bits >> 9,
                       &s_fnc, s_ci[r2], s_ck[r2], CCAP);
        }
        __syncthreads();
        ncand = min(s_fnc, CCAP);
        rneed = k - s_cbef;
      }

      // exact rank among candidates, stable tie-break (key, idx)
      for (int i = t; i < ncand; i += 256) {
        const unsigned mk = s_ck[r2][i];
        const int mi = s_ci[r2][i];
        int rank = 0;
        for (int c = 0; c < ncand; ++c) {
          const unsigned ck = s_ck[r2][c];
          const int ci = s_ci[r2][c];
          rank += (ck < mk || (ck == mk && ci < mi)) ? 1 : 0;
        }
        if (rank < rneed) {
          int s = atomicAdd(&s_nsel, 1);
          if (s < SELCAP) s_sel[s] = mi;
        }
      }

      // item row scale = 1/||item|| / T
      float iv = 0.f;
      if (t < D) iv = item[(size_t)row * D + t];
      if (t < 64) {
        float ss = iv * iv;
#pragma unroll
        for (int off = 32; off; off >>= 1) ss += __shfl_xor(ss, off, 64);
        if (t == 0) s_scale = (1.0f / sqrtf(ss)) * (1.0f / 0.07f);
      }
      __syncthreads();  // also closes the rank-append section
      if (t < D) s_itemn[t] = iv * s_scale;
      __syncthreads();
      const int nsel = min(s_nsel, SELCAP);  // == k

      float myv = (t < nsel) ? dot_sim(ent, s_sel[t], s_itemn) : -INFINITY;
      const float m = block_max(myv, s_wred, t);
      float v2 = (t < nsel) ? expf(myv - m) : 0.f;  // register reuse, no 2nd dot
      const float S = block_sum(v2, s_wred, t);

      float lp = 0.f;
      if (t < npos) {
        float sp = dot_sim(ent, s_pos[r2][t], s_itemn);
        float pm = fmaxf(sp, m);
        lp = logf(expf(sp - pm) + S * expf(m - pm)) + pm - sp;
      }
      rowloss = block_sum(lp, s_wred, t);
    }
    if (WSOUT) {
      if (t == 0) { loss[row] = valid ? rowloss : 0.f; cnt[row] = valid ? npos : 0; }
    } else {
      if (valid && t == 0) {
        atomicAdd(accum, (double)rowloss);
        atomicAdd(paircnt, npos);
      }
    }
    __syncthreads();
  }
}

// Deterministic single-block tree reduction: out = sum(loss)/sum(cnt).
__global__ __launch_bounds__(256) void reduce_out(
    const float* __restrict__ loss, const int* __restrict__ cnt, int I,
    float* __restrict__ out) {
  const int t = threadIdx.x;
  __shared__ double s_l[256];
  __shared__ int s_n[256];
  double l = 0.0;
  int n = 0;
  for (int i = t; i < I; i += 256) { l += (double)loss[i]; n += cnt[i]; }
  s_l[t] = l; s_n[t] = n;
  __syncthreads();
  for (int off = 128; off; off >>= 1) {
    if (t < off) { s_l[t] += s_l[t + off]; s_n[t] += s_n[t + off]; }
    __syncthreads();
  }
  if (t == 0) out[0] = (s_n[0] > 0) ? (float)(s_l[0] / (double)s_n[0]) : 0.f;
}

__global__ void infonce_init(double* accum, int* cnt) {
  if (threadIdx.x == 0 && blockIdx.x == 0) { accum[0] = 0.0; cnt[0] = 0; }
}

__global__ void infonce_final(const double* __restrict__ accum,
                              const int* __restrict__ cnt,
                              float* __restrict__ out) {
  if (threadIdx.x == 0 && blockIdx.x == 0) {
    int n = cnt[0];
    out[0] = (n > 0) ? (float)(accum[0] / (double)n) : 0.f;
  }
}

extern "C" void kernel_launch(void* const* d_in, const int* in_sizes, int n_in,
                              void* d_out, int out_size, void* d_ws, size_t ws_size,
                              hipStream_t stream) {
  const float* item = (const float*)d_in[0];
  const float* ent  = (const float*)d_in[1];
  const int*   adj  = (const int*)d_in[2];
  const int I = in_sizes[0] / D;   // 4096
  const int E = in_sizes[1] / D;   // 16384

  const size_t need = (size_t)I * 8;  // loss[I] f32 + cnt[I] i32
  if (ws_size >= need && (I % 2) == 0) {
    float* lossb = (float*)d_ws;
    int*   cntb  = (int*)(lossb + I);
    infonce_mono<true><<<I / 2, 256, 0, stream>>>(item, ent, adj, I, E,
                                                  lossb, cntb, nullptr, nullptr);
    reduce_out<<<1, 256, 0, stream>>>(lossb, cntb, I, (float*)d_out);
  } else {
    double* accum   = (double*)d_ws;
    int*    paircnt = (int*)((char*)d_ws + 8);
    infonce_init<<<1, 64, 0, stream>>>(accum, paircnt);
    infonce_mono<false><<<I / 2, 256, 0, stream>>>(item, ent, adj, I, E,
                                                   nullptr, nullptr, accum, paircnt);
    infonce_final<<<1, 64, 0, stream>>>(accum, paircnt, (float*)d_out);
  }
}